// Round 12
// baseline (116.146 us; speedup 1.0000x reference)
//
#include <hip/hip_runtime.h>
#include <hip/hip_bf16.h>

// SubjectLayers via bf16 MFMA 32x32x16: out[b,o,t] = sum_c W[s,o,c]*x[b,c,t] + b[s,o]
// B=128, C=64, T=8192, S=16. fp32 in/out, bf16 matrix cores.
//
// R11: single-variable experiment — read-stream chunk 1KB -> 2KB.
// Cross-round curve (clean traffic): 128B=4.38, 512B=4.70, 1KB=4.97 TB/s;
// chunk = contiguous bytes issued back-to-back per row stream. TT=512:
//  - bf16 LDS tile [64][512] = 64 KB, 2 blocks/CU (unchanged)
//  - each wave stages 16 rows x 2KB (two adjacent 1KB float4-loads per row,
//    batched 4 rows = 8 loads in flight; transient 32 VGPR, no R8-style spill)
//  - one barrier; frag reads u16 (2-way, free); stores direct from acc
//    (R10-proven clean); 4 t-steps per wave instead of 2.

typedef __attribute__((ext_vector_type(8))) short  bf16x8;   // 4 VGPRs
typedef __attribute__((ext_vector_type(16))) float f32x16;   // 16 VGPRs

namespace {
constexpr int Cdim  = 64;
constexpr int Tdim  = 8192;
constexpr int TT    = 512;        // t per block tile (2KB per row stream)
constexpr int BLOCK = 256;        // 4 waves
}

static __device__ __forceinline__ unsigned short f2bfu(float f) {
    return __builtin_bit_cast(unsigned short, __float2bfloat16(f));
}

__global__ __launch_bounds__(BLOCK, 2)
void subject_layers_r11(const float* __restrict__ x,
                        const int*   __restrict__ subj,
                        const float* __restrict__ W,
                        const float* __restrict__ bias,
                        float*       __restrict__ out) {
    __shared__ unsigned short tile[Cdim * TT];   // 64 KB bf16, x only

    const int b    = blockIdx.y;
    const int tb   = blockIdx.x;
    const int tid  = threadIdx.x;
    const int wave = tid >> 6;
    const int lane = tid & 63;
    const int hi   = lane >> 5;   // 0..1
    const int ln   = lane & 31;   // m/n index within 32-tile
    const int s    = subj[b];

    const size_t xbase = (size_t)b * Cdim * Tdim + (size_t)tb * TT;

    // ---- stage x tile as bf16. wave w owns rows g*4+w (16 rows); per row:
    //      TWO adjacent 1KB loads (cols lane*4 and 256+lane*4) back-to-back ->
    //      2KB sequential per stream. Batch 4 rows (8 loads, 32 VGPR transient).
    {
        float4 v0[4], v1[4];
        #pragma unroll
        for (int gg = 0; gg < 4; ++gg) {
            #pragma unroll
            for (int g = 0; g < 4; ++g) {
                const int row = (gg * 4 + g) * 4 + wave;
                const float* rp = x + xbase + (size_t)row * Tdim;
                v0[g] = *reinterpret_cast<const float4*>(rp + lane * 4);
                v1[g] = *reinterpret_cast<const float4*>(rp + 256 + lane * 4);
            }
            #pragma unroll
            for (int g = 0; g < 4; ++g) {
                const int row = (gg * 4 + g) * 4 + wave;
                ushort4 u0, u1;
                u0.x = f2bfu(v0[g].x); u0.y = f2bfu(v0[g].y);
                u0.z = f2bfu(v0[g].z); u0.w = f2bfu(v0[g].w);
                u1.x = f2bfu(v1[g].x); u1.y = f2bfu(v1[g].y);
                u1.z = f2bfu(v1[g].z); u1.w = f2bfu(v1[g].w);
                *reinterpret_cast<ushort4*>(&tile[row * TT + lane * 4]) = u0;
                *reinterpret_cast<ushort4*>(&tile[row * TT + 256 + lane * 4]) = u1;
            }
        }
    }

    // ---- A fragments: W[s] -> bf16 (independent of staging) ----
    // A[m][k]: m = ln, k = kb*16 + hi*8 + j  (mirrored with B -> k-perm cancels)
    bf16x8 afrag[2][4];
    const float* Wb = W + (size_t)s * Cdim * Cdim;
    #pragma unroll
    for (int ot = 0; ot < 2; ++ot) {
        #pragma unroll
        for (int kb = 0; kb < 4; ++kb) {
            const float* ap = Wb + (size_t)(ot * 32 + ln) * Cdim + kb * 16 + hi * 8;
            const float4 a0 = *reinterpret_cast<const float4*>(ap);
            const float4 a1 = *reinterpret_cast<const float4*>(ap + 4);
            bf16x8 f;
            f[0] = (short)f2bfu(a0.x); f[1] = (short)f2bfu(a0.y);
            f[2] = (short)f2bfu(a0.z); f[3] = (short)f2bfu(a0.w);
            f[4] = (short)f2bfu(a1.x); f[5] = (short)f2bfu(a1.y);
            f[6] = (short)f2bfu(a1.z); f[7] = (short)f2bfu(a1.w);
            afrag[ot][kb] = f;
        }
    }

    // ---- bias -> accumulator init ----
    // C/D: col = ln, row(reg r) = (r&3) + 8*(r>>2) + 4*hi   [m74/m101-verified]
    f32x16 bini[2];
    const float* bb = bias + (size_t)s * Cdim;
    #pragma unroll
    for (int ot = 0; ot < 2; ++ot)
        #pragma unroll
        for (int r = 0; r < 16; ++r)
            bini[ot][r] = bb[ot * 32 + (r & 3) + 8 * (r >> 2) + 4 * hi];

    __syncthreads();   // x tile ready

    // ---- per 32-t step: frag read -> MFMA -> direct acc stores ----
    // wave w owns cols [w*128, w*128+128): 4 steps of 32.
    float* ob = out + xbase;
    #pragma unroll
    for (int st = 0; st < 4; ++st) {
        const int col = wave * 128 + st * 32 + ln;

        // B[k][n]: n = ln, k = kb*16 + hi*8 + j (mirror of A); bf16 in LDS
        bf16x8 bfrag[4];
        #pragma unroll
        for (int kb = 0; kb < 4; ++kb) {
            bf16x8 f;
            #pragma unroll
            for (int j = 0; j < 8; ++j)
                f[j] = (short)tile[(kb * 16 + hi * 8 + j) * TT + col];
            bfrag[kb] = f;
        }

        #pragma unroll
        for (int ot = 0; ot < 2; ++ot) {
            f32x16 acc = bini[ot];
            #pragma unroll
            for (int kb = 0; kb < 4; ++kb)
                acc = __builtin_amdgcn_mfma_f32_32x32x16_bf16(
                    afrag[ot][kb], bfrag[kb], acc, 0, 0, 0);
            // store instr r: 2 rows x 128B full aligned lines (R10-proven)
            #pragma unroll
            for (int r = 0; r < 16; ++r)
                ob[(size_t)(ot * 32 + (r & 3) + 8 * (r >> 2) + 4 * hi) * Tdim + col]
                    = acc[r];
        }
    }
}

extern "C" void kernel_launch(void* const* d_in, const int* in_sizes, int n_in,
                              void* d_out, int out_size, void* d_ws, size_t ws_size,
                              hipStream_t stream) {
    const float* x    = (const float*)d_in[0];   // [B, C, T]
    const int*   subj = (const int*)  d_in[1];   // [B]
    const float* W    = (const float*)d_in[2];   // [S, C, C]
    const float* bias = (const float*)d_in[3];   // [S, C]
    float*       out  = (float*)d_out;           // [B, C, T]

    const int B = in_sizes[1];                   // 128
    dim3 grid(Tdim / TT, B);                     // (16, 128) = 2048 blocks
    dim3 block(BLOCK);
    hipLaunchKernelGGL(subject_layers_r11, grid, block, 0, stream,
                       x, subj, W, bias, out);
}

// Round 15
// 101.019 us; speedup vs baseline: 1.1497x; 1.1497x over previous
//
#include <hip/hip_runtime.h>
#include <hip/hip_bf16.h>

// SubjectLayers via bf16 MFMA 32x32x16: out[b,o,t] = sum_c W[s,o,c]*x[b,c,t] + b[s,o]
// B=128, C=64, T=8192, S=16. fp32 in/out, bf16 matrix cores.
//
// R12 (2nd resubmit after infra failures) = R10 (gload_lds 1KB-row staging,
// one-barrier, direct-acc stores; 104.5us) + C-split double-buffered pipeline:
//   - tile A = c-rows 0..31 (32KB), tile B = c-rows 32..63 (32KB)
//   - stage A -> bar -> {issue DMA for B, MFMA K-half 0} -> bar ->
//     {MFMA K-half 1, stores}: B's 32KB drain overlaps half0 compute
//   - accumulators (4 x f32x16) live across bar2; all indices static
//   - still 64KB LDS, 2 blocks/CU, 1KB read chunks, clean store shape

typedef __attribute__((ext_vector_type(8))) short  bf16x8;   // 4 VGPRs
typedef __attribute__((ext_vector_type(16))) float f32x16;   // 16 VGPRs

namespace {
constexpr int Cdim  = 64;
constexpr int Tdim  = 8192;
constexpr int TT    = 256;        // t per block tile
constexpr int BLOCK = 256;        // 4 waves
}

static __device__ __forceinline__ short f2bf(float f) {
    return (short)__builtin_bit_cast(unsigned short, __float2bfloat16(f));
}

__global__ __launch_bounds__(BLOCK, 2)
void subject_layers_r12(const float* __restrict__ x,
                        const int*   __restrict__ subj,
                        const float* __restrict__ W,
                        const float* __restrict__ bias,
                        float*       __restrict__ out) {
    __shared__ float tA[32 * TT];   // c-rows 0..31  (32 KB)
    __shared__ float tB[32 * TT];   // c-rows 32..63 (32 KB)

    const int b    = blockIdx.y;
    const int tb   = blockIdx.x;
    const int tid  = threadIdx.x;
    const int wave = tid >> 6;
    const int lane = tid & 63;
    const int hi   = lane >> 5;   // 0..1
    const int ln   = lane & 31;   // m/n index within 32-tile
    const int s    = subj[b];

    const size_t xbase = (size_t)b * Cdim * Tdim + (size_t)tb * TT;

    // ---- stage K-half 0 (c-rows 0..31): wave w owns rows g*4+w, g<8;
    //      one global_load_lds = one 1KB row burst ----
    #pragma unroll
    for (int g = 0; g < 8; ++g) {
        const int row = g * 4 + wave;
        __builtin_amdgcn_global_load_lds(
            (const __attribute__((address_space(1))) unsigned int*)
                (x + xbase + (size_t)row * Tdim + lane * 4),
            (__attribute__((address_space(3))) unsigned int*)
                (&tA[row * TT]),
            16, 0, 0);
    }

    // ---- A fragments: W[s] -> bf16 (independent of staging) ----
    // A[m][k]: m = ln, k = kb*16 + hi*8 + j  (mirrored with B -> k-perm cancels)
    bf16x8 afrag[2][4];
    const float* Wb = W + (size_t)s * Cdim * Cdim;
    #pragma unroll
    for (int ot = 0; ot < 2; ++ot) {
        #pragma unroll
        for (int kb = 0; kb < 4; ++kb) {
            const float* ap = Wb + (size_t)(ot * 32 + ln) * Cdim + kb * 16 + hi * 8;
            const float4 a0 = *reinterpret_cast<const float4*>(ap);
            const float4 a1 = *reinterpret_cast<const float4*>(ap + 4);
            bf16x8 f;
            f[0] = f2bf(a0.x); f[1] = f2bf(a0.y); f[2] = f2bf(a0.z); f[3] = f2bf(a0.w);
            f[4] = f2bf(a1.x); f[5] = f2bf(a1.y); f[6] = f2bf(a1.z); f[7] = f2bf(a1.w);
            afrag[ot][kb] = f;
        }
    }

    // ---- bias -> accumulator init ----
    // C/D: col = ln, row(reg r) = (r&3) + 8*(r>>2) + 4*hi   [m74/m101-verified]
    f32x16 acc[2][2];   // [st][ot], live across bar2
    {
        const float* bb = bias + (size_t)s * Cdim;
        #pragma unroll
        for (int ot = 0; ot < 2; ++ot) {
            f32x16 bi;
            #pragma unroll
            for (int r = 0; r < 16; ++r)
                bi[r] = bb[ot * 32 + (r & 3) + 8 * (r >> 2) + 4 * hi];
            acc[0][ot] = bi;
            acc[1][ot] = bi;
        }
    }

    __syncthreads();   // K-half 0 staged (vmcnt drained)

    // ---- issue DMA for K-half 1 (c-rows 32..63) — flies during half-0 MFMA ----
    #pragma unroll
    for (int g = 0; g < 8; ++g) {
        const int row = 32 + g * 4 + wave;
        __builtin_amdgcn_global_load_lds(
            (const __attribute__((address_space(1))) unsigned int*)
                (x + xbase + (size_t)row * Tdim + lane * 4),
            (__attribute__((address_space(3))) unsigned int*)
                (&tB[(row - 32) * TT]),
            16, 0, 0);
    }

    // ---- K-half 0 compute: kb = 0,1 from tA ----
    #pragma unroll
    for (int st = 0; st < 2; ++st) {
        const int col = wave * 64 + st * 32 + ln;
        bf16x8 bfrag[2];
        #pragma unroll
        for (int kb = 0; kb < 2; ++kb) {
            bf16x8 f;
            #pragma unroll
            for (int j = 0; j < 8; ++j)
                f[j] = f2bf(tA[(kb * 16 + hi * 8 + j) * TT + col]);
            bfrag[kb] = f;
        }
        #pragma unroll
        for (int ot = 0; ot < 2; ++ot) {
            acc[st][ot] = __builtin_amdgcn_mfma_f32_32x32x16_bf16(
                afrag[ot][0], bfrag[0], acc[st][ot], 0, 0, 0);
            acc[st][ot] = __builtin_amdgcn_mfma_f32_32x32x16_bf16(
                afrag[ot][1], bfrag[1], acc[st][ot], 0, 0, 0);
        }
    }

    __syncthreads();   // K-half 1 staged

    // ---- K-half 1 compute (kb = 2,3 from tB) + direct-acc stores ----
    float* ob = out + xbase;
    #pragma unroll
    for (int st = 0; st < 2; ++st) {
        const int col = wave * 64 + st * 32 + ln;
        bf16x8 bfrag[2];
        #pragma unroll
        for (int kb = 0; kb < 2; ++kb) {
            bf16x8 f;
            #pragma unroll
            for (int j = 0; j < 8; ++j)
                f[j] = f2bf(tB[(kb * 16 + hi * 8 + j) * TT + col]);
            bfrag[kb] = f;
        }
        #pragma unroll
        for (int ot = 0; ot < 2; ++ot) {
            acc[st][ot] = __builtin_amdgcn_mfma_f32_32x32x16_bf16(
                afrag[ot][2], bfrag[0], acc[st][ot], 0, 0, 0);
            acc[st][ot] = __builtin_amdgcn_mfma_f32_32x32x16_bf16(
                afrag[ot][3], bfrag[1], acc[st][ot], 0, 0, 0);
            // store instr r: 2 rows x 128B full aligned lines (R10-proven clean)
            #pragma unroll
            for (int r = 0; r < 16; ++r)
                ob[(size_t)(ot * 32 + (r & 3) + 8 * (r >> 2) + 4 * hi) * Tdim + col]
                    = acc[st][ot][r];
        }
    }
}

extern "C" void kernel_launch(void* const* d_in, const int* in_sizes, int n_in,
                              void* d_out, int out_size, void* d_ws, size_t ws_size,
                              hipStream_t stream) {
    const float* x    = (const float*)d_in[0];   // [B, C, T]
    const int*   subj = (const int*)  d_in[1];   // [B]
    const float* W    = (const float*)d_in[2];   // [S, C, C]
    const float* bias = (const float*)d_in[3];   // [S, C]
    float*       out  = (float*)d_out;           // [B, C, T]

    const int B = in_sizes[1];                   // 128
    dim3 grid(Tdim / TT, B);                     // (32, 128) = 4096 blocks
    dim3 block(BLOCK);
    hipLaunchKernelGGL(subject_layers_r12, grid, block, 0, stream,
                       x, subj, W, bias, out);
}